// Round 6
// baseline (316.824 us; speedup 1.0000x reference)
//
#include <hip/hip_runtime.h>
#include <math.h>

// VectorQuantizer: x (32768,64) f32, codebook (8192,64) f32, start/end/use_sk ints.
// Outputs concat: x_q_st (2097152 f32) | loss (1 f32) | indices (32768 as f32 values).
//
// R15 == R14 resubmitted (R5 bench failure was infrastructural: container acquire
// failed twice; no kernel signal). R14: R13 + per-slot CODE MASKS (the R9
// ingredient R10-R13 dropped). Rescue evaluates ~2.6 exact 256B code rows per
// token instead of ~2.6 x 8KB chunks (R13's hidden 680MB of L2 traffic -> ~25MB).
//  vq_sc:    sc_k exact (pairwise-8 numpy replica, f32) + cb -> bf16 rows (K=64).
//  vq_pass1: 32x32x16 MFMA filter, block = 128 tokens x 2048 codes (quarter).
//            Per (token,quarter): running local min; REGISTER sorted slots s0..s8,
//            each a PAIR (key = mono-f16<<16|cid, mask32); 64-bit bitmap of
//            running-window accepts. On accept: chunk mask = bits with
//            acc >= chunkmax - W/2 (== g_bf <= chunkmin + W, R9 semantics;
//            cross-half shfl_xor(32) merge -- accept is pair-uniform so safe).
//            Emit per quarter: 8 slot planes + 8 mask planes + 2 bitmap planes.
//            Marker (rec[7].cid=0xFFFE) iff mv(s8) <= thr_final (EXACT >=9-in-
//            final-window condition); bitmap superset covers marker quarters.
//  vq_rescue: 2048 blocks x 16 tokens x 4 waves. Phase A: wave0 reads slots+masks,
//            gthr = min+WINDOW; surviving slots expand mask bits into per-token
//            CODE list (~2.6); marker quarters push bitmap chunks as full-chunk
//            jobs. Waves1-2 stage x rows; wave3 exact sx (pairwise-8 replica).
//            Phase B: wave owns tokens 4wv..4wv+3: ONE batched pass evaluates up
//            to 32 codes at 2 lanes/code with the BIT-EXACT R1 numpy-replica
//            arithmetic (j0-3/j4-7 split, tt = s03+s47 via shfl_xor(.,1),
//            IEEE-commutative); chunk jobs = full-chunk passes (rare); overflow
//            -> all-chunk brute force (~never). Lex-min (enc(d),k); fused
//            epilogue with the EXACT legacy loss tree (6x shfl_down,
//            (s0+s1)+(s2+s3), partial[token>>2]).
// Exactness: ref argmin k*: g_bf(k*) <= chunkmin + 2*err_bf (1.6e-4) < chunkmin+W
// -> k* in its chunk's mask. Its chunk's mv <= global min + budget < gthr -> the
// chunk is in slots (or marker fires and bitmap/full-chunk eval covers it) -> k*
// always evaluated exactly; out-of-range mask bits filtered by the k in [s,e)
// check. Lex-min over a superset containing the reference argmin == reference.
// DO NOT change the exact-path arithmetic: inter-code d gaps are ~1 ulp of d.

#define N_E    8192
#define EDIM   64
#define NTOK   32768
#define NELEM  (NTOK * EDIM)
#define CSZ    32                  // chunk size
#define WINDOW 3e-4f
#define TTOK   128                 // pass-1 tokens per block
#define TCODE  2048                // pass-1 codes per block (quarter)
#define SROW   72                  // Cs stride (ushorts; 36 dwords == 4 mod 8)
#define TOKB   16                  // rescue tokens per block
#define CCAP   64                  // rescue per-token code-list capacity
#define KCAP   16                  // rescue per-token chunk-job capacity

typedef __attribute__((ext_vector_type(8)))  short          short8;
typedef __attribute__((ext_vector_type(8)))  unsigned short ushort8v;
typedef __attribute__((ext_vector_type(16))) float          f32x16;

__device__ __forceinline__ unsigned short f2bf(float f) {   // RTNE f32->bf16 bits
  unsigned int u = __float_as_uint(f);
  return (unsigned short)((u + 0x7FFFu + ((u >> 16) & 1u)) >> 16);
}
__device__ __forceinline__ unsigned short f2h(float f) {
  union { _Float16 h; unsigned short u; } cv; cv.h = (_Float16)f; return cv.u;
}
__device__ __forceinline__ float h2f(unsigned short b) {
  union { _Float16 h; unsigned short u; } cv; cv.u = b; return (float)cv.h;
}
__device__ __forceinline__ float max16(const f32x16 a) {
  float m0 = fmaxf(fmaxf(a[0], a[1]),   fmaxf(a[2], a[3]));
  float m1 = fmaxf(fmaxf(a[4], a[5]),   fmaxf(a[6], a[7]));
  float m2 = fmaxf(fmaxf(a[8], a[9]),   fmaxf(a[10], a[11]));
  float m3 = fmaxf(fmaxf(a[12], a[13]), fmaxf(a[14], a[15]));
  return fmaxf(fmaxf(m0, m1), fmaxf(m2, m3));
}
// sx = np.sum(x*x) pairwise-8 replica (reads a 64-f32 row via float4*)
__device__ __forceinline__ float sx_of(const float4* xl4) {
#pragma clang fp contract(off)
  float a0=0,a1=0,a2=0,a3=0,a4=0,a5=0,a6=0,a7=0;
#pragma unroll
  for (int i = 0; i < 8; ++i) {
    float4 pA = xl4[2*i], pB = xl4[2*i+1];
    a0 += pA.x * pA.x; a1 += pA.y * pA.y; a2 += pA.z * pA.z; a3 += pA.w * pA.w;
    a4 += pB.x * pB.x; a5 += pB.y * pB.y; a6 += pB.z * pB.z; a7 += pB.w * pB.w;
  }
  return ((a0+a1) + (a2+a3)) + ((a4+a5) + (a6+a7));
}

// ---------------- sc (exact pairwise-8) + cb -> bf16 rows (K=64) --------------------
__global__ __launch_bounds__(256) void vq_sc(const float* __restrict__ cb,
                                             float* __restrict__ sc,
                                             unsigned short* __restrict__ cbf) {
#pragma clang fp contract(off)
  int r = blockIdx.x * 256 + threadIdx.x;
  const float4* c4 = (const float4*)(cb + (size_t)r * EDIM);
  float sval = sx_of(c4);
  sc[r] = sval;
  unsigned short* dst = cbf + (size_t)r * EDIM;
#pragma unroll
  for (int h = 0; h < 8; ++h) {
    float4 fA = c4[2*h], fB = c4[2*h+1];
    ushort8v o = {f2bf(fA.x), f2bf(fA.y), f2bf(fA.z), f2bf(fA.w),
                  f2bf(fB.x), f2bf(fB.y), f2bf(fB.z), f2bf(fB.w)};
    *(ushort8v*)&dst[h * 8] = o;
  }
}

// ---------------- pass 1: MFMA filter -> slot/mask/bitmap records -------------------
// Frags: A[m=lane&31][k=8*(lane>>5)+j] (codes), B same (tokens),
// D: col=lane&31 (token), row=(reg&3)+8*(reg>>2)+4*(lane>>5) (code).
// Plane layout (72 planes x NTOK u32): [0..31] slots (q*8+j), [32..63] masks
// (32+q*8+j), [64..71] bitmaps (64+q*2 lo, 65+q*2 hi).
__global__ __launch_bounds__(256, 3) void vq_pass1(
    const float* __restrict__ x, const unsigned short* __restrict__ cbf,
    unsigned int* __restrict__ cand,
    const int* __restrict__ p_start, const int* __restrict__ p_end) {
  __shared__ unsigned short Cs[128 * SROW];     // 18432 B
  int tid = threadIdx.x;
  int tb = blockIdx.x;    // token split [0,256)
  int cbk = blockIdx.y;   // code split  [0,4)  (the "quarter")
  int s = *p_start, e = *p_end;

  int lane = tid & 63, wv = tid >> 6;
  int half = lane >> 5, ln = lane & 31;
  int tokbase = wv * 32;

  // ---- stage first code tile: 128 rows x 8 ushort8 (linear, coalesced) ----
  const ushort8v* cg0 = (const ushort8v*)(cbf + (size_t)cbk * TCODE * EDIM);
#pragma unroll
  for (int p = 0; p < 4; ++p) {
    int idx = tid + p * 256;
    int row = idx >> 3, h = idx & 7;
    *(ushort8v*)&Cs[row * SROW + h * 8] = cg0[idx];
  }

  // ---- B fragments straight from global (fused f32 -> bf16) ----
  short8 bfr[4];
  {
    const float* xrow =
        x + (size_t)(tb * TTOK + tokbase + ln) * EDIM + half * 8;
#pragma unroll
    for (int ks = 0; ks < 4; ++ks) {
      float4 fA = *(const float4*)(xrow + ks * 16);
      float4 fB = *(const float4*)(xrow + ks * 16 + 4);
      short8 v = {(short)f2bf(fA.x), (short)f2bf(fA.y), (short)f2bf(fA.z),
                  (short)f2bf(fA.w), (short)f2bf(fB.x), (short)f2bf(fB.y),
                  (short)f2bf(fB.z), (short)f2bf(fB.w)};
      bfr[ks] = v;
    }
  }
  __syncthreads();

  // register sorted slot pairs (key asc; key = mono-f16<<16 | local_chunk_id)
  unsigned s0=~0u,s1=~0u,s2=~0u,s3=~0u,s4=~0u,s5=~0u,s6=~0u,s7=~0u,s8=~0u;
  unsigned m0=0,m1=0,m2=0,m3=0,m4=0,m5=0,m6=0,m7=0,m8=0;
  unsigned long long bmap = 0ull;
  float lminf = INFINITY;

  for (int nb = 0; nb < 16; ++nb) {
    ushort8v creg[4];
    if (nb < 15) {                               // prefetch next tile into registers
      const ushort8v* cg =
          (const ushort8v*)(cbf + ((size_t)cbk * TCODE + (nb + 1) * 128) * EDIM);
#pragma unroll
      for (int p = 0; p < 4; ++p) creg[p] = cg[tid + p * 256];
    }
    f32x16 acc[4];
#pragma unroll
    for (int ct = 0; ct < 4; ++ct) acc[ct] = (f32x16)0.0f;
#pragma unroll
    for (int ks = 0; ks < 4; ++ks)
#pragma unroll
      for (int ct = 0; ct < 4; ++ct) {
        short8 a = *(const short8*)&Cs[(ct*32 + ln) * SROW + ks*16 + half*8];
        acc[ct] = __builtin_amdgcn_mfma_f32_32x32x16_bf16(a, bfr[ks],
                                                          acc[ct], 0, 0, 0);
      }
    __syncthreads();                             // all Cs reads done
    if (nb < 15) {
#pragma unroll
      for (int p = 0; p < 4; ++p) {
        int idx = tid + p * 256;
        int row = idx >> 3, h = idx & 7;
        *(ushort8v*)&Cs[row * SROW + h * 8] = creg[p];
      }
    }
    // epilogue (registers only): chunk max -> f16 min -> slots(+mask)/bitmap
    int cbase0 = cbk * TCODE + nb * 128;
#pragma unroll
    for (int ct = 0; ct < 4; ++ct) {
      int c0 = cbase0 + ct * 32;
      bool full = (c0 >= s) && (c0 + 32 <= e);
      float v;
      if (full) {
        v = max16(acc[ct]);
      } else {
        v = -INFINITY;
#pragma unroll
        for (int r = 0; r < 16; ++r) {
          int code = c0 + (r & 3) + 8 * (r >> 2) + 4 * half;
          if (code >= s && code < e) v = fmaxf(v, acc[ct][r]);
        }
      }
      v = fmaxf(v, __shfl_xor(v, 32, 64));       // chunk max in f32 acc space
      unsigned short hh = f2h(-2.0f * v);        // f16 chunk minimum (record value)
      float mvf = h2f(hh);
      lminf = fminf(lminf, mvf);
      if (mvf <= lminf + WINDOW) {               // running-window accept (pair-uniform)
        bmap |= 1ull << (nb * 4 + ct);
        float t = v - WINDOW * 0.5f;             // acc>=t  <=>  g_bf<=chunkmin+W
        unsigned b = 0;
#pragma unroll
        for (int r = 0; r < 16; ++r) {
          int pos = (r & 3) + 8 * (r >> 2) + 4 * half;
          if (acc[ct][r] >= t) b |= (1u << pos);
        }
        b |= __shfl_xor(b, 32, 64);              // merge row-half groups (safe: uniform)
        unsigned mono = (unsigned)hh ^ ((hh & 0x8000u) ? 0xFFFFu : 0x8000u);
        unsigned p = (mono << 16) | (unsigned)(nb * 4 + ct);
        unsigned pm = b;
        if (p < s8) {                            // static bubble insert of the PAIR
#define INS2_(SK, SM) { bool lt_ = p < (SK); unsigned tk_ = (SK), tm_ = (SM); \
          if (lt_) { (SK) = p; (SM) = pm; p = tk_; pm = tm_; } }
          INS2_(s0,m0) INS2_(s1,m1) INS2_(s2,m2) INS2_(s3,m3) INS2_(s4,m4)
          INS2_(s5,m5) INS2_(s6,m6) INS2_(s7,m7) INS2_(s8,m8)
#undef INS2_
        }
      }
    }
    __syncthreads();                             // Cs writes visible before next MFMA
  }

  // ---- emit record (half==0 lanes; plane-coalesced) ----
  if (!half) {
    float thr = lminf + WINDOW;
    unsigned rec[8], msk[8];
#define EMIT_(J, S, M) { unsigned mono_ = (S) >> 16; \
    unsigned hh_ = (mono_ & 0x8000u) ? (mono_ ^ 0x8000u) : (mono_ ^ 0xFFFFu); \
    float v_ = h2f((unsigned short)hh_); \
    rec[J] = (v_ <= thr) ? ((hh_ << 16) | ((S) & 0xFFFFu)) : 0xFFFFFFFFu; \
    msk[J] = (M); }
    EMIT_(0, s0, m0) EMIT_(1, s1, m1) EMIT_(2, s2, m2) EMIT_(3, s3, m3)
    EMIT_(4, s4, m4) EMIT_(5, s5, m5) EMIT_(6, s6, m6) EMIT_(7, s7, m7)
#undef EMIT_
    {
      unsigned mono_ = s8 >> 16;
      unsigned hh_ = (mono_ & 0x8000u) ? (mono_ ^ 0x8000u) : (mono_ ^ 0xFFFFu);
      float v8 = h2f((unsigned short)hh_);       // NaN when <9 accepts -> false
      if (v8 <= thr) rec[7] = 0x0000FFFEu;       // EXACT overflow marker
    }
    int token = tb * TTOK + tokbase + ln;
#pragma unroll
    for (int j = 0; j < 8; ++j) {
      cand[(size_t)(cbk * 8 + j) * NTOK + token] = rec[j];
      cand[(size_t)(32 + cbk * 8 + j) * NTOK + token] = msk[j];
    }
    cand[(size_t)(64 + cbk * 2) * NTOK + token] = (unsigned)(bmap & 0xFFFFFFFFull);
    cand[(size_t)(65 + cbk * 2) * NTOK + token] = (unsigned)(bmap >> 32);
  }
}

// ---------------- pass 2: code-list rescue + fused epilogue -------------------------
__global__ __launch_bounds__(256) void vq_rescue(
    const float* __restrict__ x, const float* __restrict__ cb,
    const float* __restrict__ sc, const unsigned int* __restrict__ cand,
    float* __restrict__ out_xq, float* __restrict__ out_idx,
    float* __restrict__ partial,
    const int* __restrict__ p_start, const int* __restrict__ p_end) {
#pragma clang fp contract(off)
  __shared__ float xsh[TOKB][64];                 // 4 KB staged x rows
  __shared__ float sxs[TOKB];                     // exact sx per token
  __shared__ unsigned short lst[TOKB][CCAP];      // per-token candidate CODE list
  __shared__ unsigned short clst[TOKB][KCAP];     // per-token full-chunk jobs
  __shared__ int ccnt[TOKB], kcnt[TOKB];
  __shared__ unsigned bfflag;
  int tid  = threadIdx.x;
  int wv   = tid >> 6;
  int lane = tid & 63;
  int blk  = blockIdx.x;
  int s = *p_start, e = *p_end;

  if (tid < TOKB) { ccnt[tid] = 0; kcnt[tid] = 0; }
  if (tid == 0) bfflag = 0u;
  __syncthreads();

  // ---- phase A (split across waves; one barrier) --------------------------------
  if (tid < 64) {
    // wave 0: slots+masks -> gthr -> per-token code list / chunk jobs
    int tl = tid >> 2, q = tid & 3;
    int gtok = blk * TOKB + tl;
    unsigned rv[8], mk[8];
#pragma unroll
    for (int j = 0; j < 8; ++j) {
      rv[j] = cand[(size_t)(q * 8 + j) * NTOK + gtok];
      mk[j] = cand[(size_t)(32 + q * 8 + j) * NTOK + gtok];
    }
    float m = INFINITY;
#pragma unroll
    for (int j = 0; j < 8; ++j) {
      unsigned cid = rv[j] & 0xFFFFu;
      float v = (cid < 64u) ? h2f((unsigned short)(rv[j] >> 16)) : INFINITY;
      m = fminf(m, v);
    }
    m = fminf(m, __shfl_xor(m, 1, 64));          // combine the token's 4 quarters
    m = fminf(m, __shfl_xor(m, 2, 64));
    float thr = m + WINDOW;                      // global window threshold
    bool marker = ((rv[7] & 0xFFFFu) == 0xFFFEu);
    if (!marker) {
#pragma unroll
      for (int j = 0; j < 8; ++j) {
        unsigned cid = rv[j] & 0xFFFFu;
        if (cid < 64u && h2f((unsigned short)(rv[j] >> 16)) <= thr) {
          unsigned bits = mk[j];
          int n = __popc(bits);
          int base = atomicAdd(&ccnt[tl], n);
          int kb = (q * 64 + (int)cid) * CSZ;    // global code base of the chunk
          while (bits) {
            int bpos = __ffs(bits) - 1; bits &= bits - 1;
            if (base < CCAP) lst[tl][base] = (unsigned short)(kb + bpos);
            else atomicOr(&bfflag, 1u << tl);
            ++base;
          }
        }
      }
    } else {
      unsigned cid0 = rv[0] & 0xFFFFu;           // slot0 = quarter-local min
      float v0 = (cid0 < 64u) ? h2f((unsigned short)(rv[0] >> 16)) : INFINITY;
      if (v0 <= thr) {                           // quarter can contain survivors
        unsigned b0 = cand[(size_t)(64 + q * 2) * NTOK + gtok];
        unsigned b1 = cand[(size_t)(65 + q * 2) * NTOK + gtok];
        int n = __popc(b0) + __popc(b1);
        int base = atomicAdd(&kcnt[tl], n);
        while (b0) { int j = __ffs(b0) - 1; b0 &= b0 - 1;
          if (base < KCAP) clst[tl][base] = (unsigned short)(q * 64 + j);
          else atomicOr(&bfflag, 1u << tl); ++base; }
        while (b1) { int j = __ffs(b1) - 1; b1 &= b1 - 1;
          if (base < KCAP) clst[tl][base] = (unsigned short)(q * 64 + 32 + j);
          else atomicOr(&bfflag, 1u << tl); ++base; }
      }
    }
  } else if (tid < 192) {
    // waves 1-2: stage x rows (coalesced: 8 threads x 32B per 256B row)
    int t = tid - 64;
    int tl = t >> 3, seg = t & 7;
    const float4* xg = (const float4*)(x + (size_t)(blk * TOKB + tl) * EDIM + seg * 8);
    float4 A = xg[0], B = xg[1];
    *(float4*)&xsh[tl][seg * 8]     = A;
    *(float4*)&xsh[tl][seg * 8 + 4] = B;
  } else if (tid < 192 + TOKB) {
    // wave 3: exact sx per token (serial pairwise-8 replica, from global/L2)
    int tl = tid - 192;
    sxs[tl] = sx_of((const float4*)(x + (size_t)(blk * TOKB + tl) * EDIM));
  }
  __syncthreads();

  // exact single-code eval, 2 lanes/code: lane h5 covers t[4*h5..4*h5+3];
  // tt = s03 + s47 via shfl_xor(.,1) -- IEEE add commutative -> both lanes equal.
#define EVAL_CODE_BODY(K_, XL4, SX, BP) do {                                   \
    const float4* c4_ = (const float4*)(cb + (size_t)(K_) * EDIM);             \
    float t0_=0.0f,t1_=0.0f,t2_=0.0f,t3_=0.0f;                                 \
    _Pragma("unroll")                                                          \
    for (int i_ = 0; i_ < 8; ++i_) {             /* elements ascending i */    \
      float4 v_ = c4_[2*i_ + h5_];                                             \
      float4 p_ = (XL4)[2*i_ + h5_];                                           \
      t0_ += v_.x * p_.x; t1_ += v_.y * p_.y;                                  \
      t2_ += v_.z * p_.z; t3_ += v_.w * p_.w;                                  \
    }                                                                          \
    s2_ = (t0_ + t1_) + (t2_ + t3_);             /* s03 (h5=0) / s47 (h5=1) */ \
    (void)0;                                                                   \
  } while (0)

#define FINISH_CODE(K_, ACT, SX, BP) do {                                      \
    float tt_ = s2_ + __shfl_xor(s2_, 1, 64);                                  \
    if ((ACT) && (K_) >= s && (K_) < e) {                                      \
      float d_ = ((SX) + sc[K_]) - 2.0f * tt_;                                 \
      unsigned db_ = __float_as_uint(d_);                                      \
      unsigned en_ = db_ ^ ((unsigned)((int)db_ >> 31) | 0x80000000u);         \
      unsigned long long pk_ = ((unsigned long long)en_ << 32) | (unsigned)(K_);\
      if (pk_ < (BP)) (BP) = pk_;                                              \
    }                                                                          \
  } while (0)

  // ---- phase B: wave wv owns tokens 4wv..4wv+3 (= one legacy partial group) -----
  float sg[4];
#pragma unroll
  for (int ti = 0; ti < 4; ++ti) {
    int tl = wv * 4 + ti;
    int gtok = blk * TOKB + tl;
    const float4* xl4 = (const float4*)xsh[tl];
    float sx = sxs[tl];
    unsigned long long bp = ~0ull;
    int ci_ = lane >> 1, h5_ = lane & 1;
    if ((bfflag >> tl) & 1u) {                   // overflow (~never): brute force
      for (int ch = 0; ch < 256; ++ch) {
        int k_ = ch * CSZ + ci_;
        float s2_;
        EVAL_CODE_BODY(k_, xl4, sx, bp);
        FINISH_CODE(k_, true, sx, bp);
      }
    } else {
      int nc = ccnt[tl]; if (nc > CCAP) nc = CCAP;
      for (int b0 = 0; b0 < nc; b0 += 32) {      // usually exactly one batch
        int nb = nc - b0; if (nb > 32) nb = 32;
        bool act = ci_ < nb;
        int k_ = act ? (int)lst[tl][b0 + ci_] : 0;
        float s2_ = 0.0f;
        if (act) EVAL_CODE_BODY(k_, xl4, sx, bp);
        FINISH_CODE(k_, act, sx, bp);
      }
      int nk = kcnt[tl]; if (nk > KCAP) nk = KCAP;
      for (int i = 0; i < nk; ++i) {             // full-chunk jobs (rare)
        int k_ = (int)clst[tl][i] * CSZ + ci_;
        float s2_;
        EVAL_CODE_BODY(k_, xl4, sx, bp);
        FINISH_CODE(k_, true, sx, bp);
      }
    }
#pragma unroll
    for (int off = 32; off >= 1; off >>= 1) {    // lex-min (d asc, k asc)
      unsigned long long o = __shfl_xor(bp, off, 64);
      if (o < bp) bp = o;
    }
    int bidx = (int)(unsigned)(bp & 0xFFFFFFFFull) & (N_E - 1);

    float xx = xsh[tl][lane];
    float qv = cb[(size_t)bidx * EDIM + lane];
    float diff = qv - xx;                              // fl(x_q - x)
    out_xq[(size_t)gtok * EDIM + lane] = xx + diff;    // fl(x + fl(x_q - x))
    if (lane == 0) out_idx[gtok] = (float)bidx;
    float l = diff * diff;
#pragma unroll
    for (int off = 32; off >= 1; off >>= 1) l += __shfl_down(l, off, 64);
    sg[ti] = l;                                  // legacy per-token tree
  }
#undef EVAL_CODE_BODY
#undef FINISH_CODE
  if (lane == 0)
    partial[blk * 4 + wv] = (sg[0] + sg[1]) + (sg[2] + sg[3]);
}

// ---------------- final loss reduction ----------------------------------------------
__global__ __launch_bounds__(256) void vq_loss(const float* __restrict__ partial,
                                               float* __restrict__ out_loss) {
  int tid = threadIdx.x;
  float s = 0.0f;
  for (int i = tid; i < NTOK / 4; i += 256) s += partial[i];
#pragma unroll
  for (int off = 32; off >= 1; off >>= 1) s += __shfl_down(s, off, 64);
  __shared__ float sdata[4];
  if ((tid & 63) == 0) sdata[tid >> 6] = s;
  __syncthreads();
  if (tid == 0) {
    float total = (sdata[0] + sdata[1]) + (sdata[2] + sdata[3]);
    float m = total * (1.0f / (float)NELEM);
    out_loss[0] = m + 0.25f * m;
  }
}

// ---------------- launch -------------------------------------------------------------
extern "C" void kernel_launch(void* const* d_in, const int* in_sizes, int n_in,
                              void* d_out, int out_size, void* d_ws, size_t ws_size,
                              hipStream_t stream) {
  const float* x  = (const float*)d_in[0];
  const float* cb = (const float*)d_in[1];
  const int* p_start = (const int*)d_in[2];
  const int* p_end   = (const int*)d_in[3];

  float* ws = (float*)d_ws;
  float* sc      = ws;                                            // 8192 f
  float* partial = ws + N_E;                                      // 8192 f
  unsigned short* cbf  = (unsigned short*)(ws + 2 * N_E);         // 8192*64 us (1MB)
  unsigned int*   cand = (unsigned int*)(cbf + (size_t)N_E * EDIM); // 72 planes x NTOK u32 (9.4MB)

  float* out      = (float*)d_out;
  float* out_xq   = out;                 // 2097152
  float* out_loss = out + NELEM;         // 1
  float* out_idx  = out + NELEM + 1;     // 32768

  vq_sc<<<N_E / 256, 256, 0, stream>>>(cb, sc, cbf);
  dim3 g1(NTOK / TTOK, N_E / TCODE);
  vq_pass1<<<g1, 256, 0, stream>>>(x, cbf, cand, p_start, p_end);
  vq_rescue<<<NTOK / TOKB, 256, 0, stream>>>(x, cb, sc, cand, out_xq, out_idx,
                                             partial, p_start, p_end);
  vq_loss<<<1, 256, 0, stream>>>(partial, out_loss);
}

// Round 7
// 183.076 us; speedup vs baseline: 1.7306x; 1.7306x over previous
//
#include <hip/hip_runtime.h>
#include <math.h>

// VectorQuantizer: x (32768,64) f32, codebook (8192,64) f32, start/end/use_sk ints.
// Outputs concat: x_q_st (2097152 f32) | loss (1 f32) | indices (32768 as f32 values).
//
// R16: cliff-free rescue + R0-shape pass1.
//  - R15's rescue dur (158us @ 6.6% occupancy) was a STRAGGLER TAIL: kcnt>KCAP(16)
//    set bfflag -> 256-chunk x 4-token brute force (~130us) in ~2-4% of blocks.
//    Fix: KCAP=288 (>= structural max 256), code-list overflow -> chunk job (exact:
//    chunk eval SUPERSET of mask bits), marker quarter -> bmap chunk jobs (skip its
//    slots, subsumed). NO brute-force path exists anymore.
//  - pass1 back to TTOK=256 (R0's proven two-token-group frame; R15's TTOK=128
//    halved arithmetic intensity -> ~140us). Masks computed UNCONDITIONALLY for
//    both token groups (shfl_xor(32) merges need exec-uniform lanes) then selected
//    and slot-inserted per-thread.
//  vq_sc:    sc_k exact (pairwise-8 numpy replica, f32) + cb -> bf16 rows (K=64).
//  vq_pass1: 32x32x16 MFMA filter, block = 256 tokens x 2048 codes (quarter).
//            Per (token,quarter): running local min; REGISTER sorted slots s0..s8,
//            each (key = mono-f16<<16|cid, mask32); 64-bit bitmap of running-window
//            accepts. Chunk mask = bits with acc >= chunkmax - W/2 (== g_bf <=
//            chunkmin + W, R9 semantics). Emit 8 slot + 8 mask + 2 bitmap planes.
//            Marker (rec[7].cid=0xFFFE) iff mv(s8) <= thr_final (EXACT >=9-in-
//            final-window); bitmap superset covers marker quarters.
//  vq_rescue: 2048 blocks x 16 tokens x 4 waves. Phase A: wave0 slots+masks ->
//            gthr = min+WINDOW -> per-token CODE list (~2.6 codes) + chunk jobs;
//            waves1-2 stage x rows; wave3 exact sx. Phase B: wave owns tokens
//            4wv..4wv+3: batched code eval at 2 lanes/code with the BIT-EXACT R1
//            numpy-replica arithmetic (j0-3/j4-7 split, tt = s03+s47 via
//            shfl_xor(.,1), IEEE-commutative); chunk jobs = 32-code passes.
//            Lex-min (enc(d),k); fused epilogue with the EXACT legacy loss tree.
// Exactness: ref argmin k*: g_bf(k*) <= chunkmin + 2*err_bf (1.6e-4) < chunkmin+W
// -> k* in its chunk's mask. Its chunk's mv <= gmin + budget < gthr -> chunk in
// slots (pushed as codes, or as a chunk job on list overflow) or marker fires and
// its bmap chunk job covers it -> k* always evaluated exactly; range filtered by
// k in [s,e). Lex-min over a superset containing the reference argmin == reference.
// DO NOT change the exact-path arithmetic: inter-code d gaps are ~1 ulp of d.

#define N_E    8192
#define EDIM   64
#define NTOK   32768
#define NELEM  (NTOK * EDIM)
#define CSZ    32                  // chunk size
#define WINDOW 3e-4f
#define TTOK   256                 // pass-1 tokens per block (R0 shape)
#define TCODE  2048                // pass-1 codes per block (quarter)
#define SROW   72                  // Cs stride (ushorts; 36 dwords == 4 mod 8)
#define TOKB   16                  // rescue tokens per block
#define CCAP   64                  // rescue per-token code-list capacity
#define KCAP   288                 // rescue per-token chunk-job capacity (structural max 256)

typedef __attribute__((ext_vector_type(8)))  short          short8;
typedef __attribute__((ext_vector_type(8)))  unsigned short ushort8v;
typedef __attribute__((ext_vector_type(16))) float          f32x16;

__device__ __forceinline__ unsigned short f2bf(float f) {   // RTNE f32->bf16 bits
  unsigned int u = __float_as_uint(f);
  return (unsigned short)((u + 0x7FFFu + ((u >> 16) & 1u)) >> 16);
}
__device__ __forceinline__ unsigned short f2h(float f) {
  union { _Float16 h; unsigned short u; } cv; cv.h = (_Float16)f; return cv.u;
}
__device__ __forceinline__ float h2f(unsigned short b) {
  union { _Float16 h; unsigned short u; } cv; cv.u = b; return (float)cv.h;
}
__device__ __forceinline__ float max16(const f32x16 a) {
  float m0 = fmaxf(fmaxf(a[0], a[1]),   fmaxf(a[2], a[3]));
  float m1 = fmaxf(fmaxf(a[4], a[5]),   fmaxf(a[6], a[7]));
  float m2 = fmaxf(fmaxf(a[8], a[9]),   fmaxf(a[10], a[11]));
  float m3 = fmaxf(fmaxf(a[12], a[13]), fmaxf(a[14], a[15]));
  return fmaxf(fmaxf(m0, m1), fmaxf(m2, m3));
}
// sx = np.sum(x*x) pairwise-8 replica (reads a 64-f32 row via float4*)
__device__ __forceinline__ float sx_of(const float4* xl4) {
#pragma clang fp contract(off)
  float a0=0,a1=0,a2=0,a3=0,a4=0,a5=0,a6=0,a7=0;
#pragma unroll
  for (int i = 0; i < 8; ++i) {
    float4 pA = xl4[2*i], pB = xl4[2*i+1];
    a0 += pA.x * pA.x; a1 += pA.y * pA.y; a2 += pA.z * pA.z; a3 += pA.w * pA.w;
    a4 += pB.x * pB.x; a5 += pB.y * pB.y; a6 += pB.z * pB.z; a7 += pB.w * pB.w;
  }
  return ((a0+a1) + (a2+a3)) + ((a4+a5) + (a6+a7));
}

// ---------------- sc (exact pairwise-8) + cb -> bf16 rows (K=64) --------------------
__global__ __launch_bounds__(256) void vq_sc(const float* __restrict__ cb,
                                             float* __restrict__ sc,
                                             unsigned short* __restrict__ cbf) {
#pragma clang fp contract(off)
  int r = blockIdx.x * 256 + threadIdx.x;
  const float4* c4 = (const float4*)(cb + (size_t)r * EDIM);
  float sval = sx_of(c4);
  sc[r] = sval;
  unsigned short* dst = cbf + (size_t)r * EDIM;
#pragma unroll
  for (int h = 0; h < 8; ++h) {
    float4 fA = c4[2*h], fB = c4[2*h+1];
    ushort8v o = {f2bf(fA.x), f2bf(fA.y), f2bf(fA.z), f2bf(fA.w),
                  f2bf(fB.x), f2bf(fB.y), f2bf(fB.z), f2bf(fB.w)};
    *(ushort8v*)&dst[h * 8] = o;
  }
}

// ---------------- pass 1: MFMA filter -> slot/mask/bitmap records -------------------
// Frags: A[m=lane&31][k=8*(lane>>5)+j] (codes), B same (tokens),
// D: col=lane&31 (token), row=(reg&3)+8*(reg>>2)+4*(lane>>5) (code).
// Plane layout (72 planes x NTOK u32): [0..31] slots (q*8+j), [32..63] masks
// (32+q*8+j), [64..71] bitmaps (64+q*2 lo, 65+q*2 hi).
__global__ __launch_bounds__(256, 2) void vq_pass1(
    const float* __restrict__ x, const unsigned short* __restrict__ cbf,
    unsigned int* __restrict__ cand,
    const int* __restrict__ p_start, const int* __restrict__ p_end) {
  __shared__ unsigned short Cs[128 * SROW];     // 18432 B
  int tid = threadIdx.x;
  int tb = blockIdx.x;    // token split [0,128)
  int cbk = blockIdx.y;   // code split  [0,4)  (the "quarter")
  int s = *p_start, e = *p_end;

  int lane = tid & 63, wv = tid >> 6;
  int half = lane >> 5, ln = lane & 31;
  int tokbase = wv * 64;

  // ---- stage first code tile: 128 rows x 8 ushort8 (linear, coalesced) ----
  const ushort8v* cg0 = (const ushort8v*)(cbf + (size_t)cbk * TCODE * EDIM);
#pragma unroll
  for (int p = 0; p < 4; ++p) {
    int idx = tid + p * 256;
    int row = idx >> 3, h = idx & 7;
    *(ushort8v*)&Cs[row * SROW + h * 8] = cg0[idx];
  }

  // ---- B fragments straight from global (fused f32 -> bf16), both token groups ----
  short8 bfr[2][4];
#pragma unroll
  for (int tg = 0; tg < 2; ++tg) {
    const float* xrow =
        x + (size_t)(tb * TTOK + tokbase + tg * 32 + ln) * EDIM + half * 8;
#pragma unroll
    for (int ks = 0; ks < 4; ++ks) {
      float4 fA = *(const float4*)(xrow + ks * 16);
      float4 fB = *(const float4*)(xrow + ks * 16 + 4);
      short8 v = {(short)f2bf(fA.x), (short)f2bf(fA.y), (short)f2bf(fA.z),
                  (short)f2bf(fA.w), (short)f2bf(fB.x), (short)f2bf(fB.y),
                  (short)f2bf(fB.z), (short)f2bf(fB.w)};
      bfr[tg][ks] = v;
    }
  }
  __syncthreads();

  // register sorted slot pairs for THIS thread's token (tg == half);
  // key asc; key = mono-f16<<16 | local_chunk_id
  unsigned s0=~0u,s1=~0u,s2=~0u,s3=~0u,s4=~0u,s5=~0u,s6=~0u,s7=~0u,s8=~0u;
  unsigned m0=0,m1=0,m2=0,m3=0,m4=0,m5=0,m6=0,m7=0,m8=0;
  unsigned long long bmap = 0ull;
  float lminf = INFINITY;

  for (int nb = 0; nb < 16; ++nb) {
    ushort8v creg[4];
    if (nb < 15) {                               // prefetch next tile into registers
      const ushort8v* cg =
          (const ushort8v*)(cbf + ((size_t)cbk * TCODE + (nb + 1) * 128) * EDIM);
#pragma unroll
      for (int p = 0; p < 4; ++p) creg[p] = cg[tid + p * 256];
    }
    f32x16 acc[2][4];
#pragma unroll
    for (int tg = 0; tg < 2; ++tg)
#pragma unroll
      for (int ct = 0; ct < 4; ++ct) acc[tg][ct] = (f32x16)0.0f;
#pragma unroll
    for (int ks = 0; ks < 4; ++ks)
#pragma unroll
      for (int ct = 0; ct < 4; ++ct) {
        short8 a = *(const short8*)&Cs[(ct*32 + ln) * SROW + ks*16 + half*8];
        acc[0][ct] = __builtin_amdgcn_mfma_f32_32x32x16_bf16(a, bfr[0][ks],
                                                             acc[0][ct], 0, 0, 0);
        acc[1][ct] = __builtin_amdgcn_mfma_f32_32x32x16_bf16(a, bfr[1][ks],
                                                             acc[1][ct], 0, 0, 0);
      }
    __syncthreads();                             // all Cs reads done
    if (nb < 15) {
#pragma unroll
      for (int p = 0; p < 4; ++p) {
        int idx = tid + p * 256;
        int row = idx >> 3, h = idx & 7;
        *(ushort8v*)&Cs[row * SROW + h * 8] = creg[p];
      }
    }
    // epilogue (registers only; overlaps Cs writes): chunk max+mask both tgs
    // (UNCONDITIONAL: the shfl_xor(32) merges require exec-uniform lanes),
    // then per-thread select (tg == half) and divergent slot insert.
    int cbase0 = cbk * TCODE + nb * 128;
#pragma unroll
    for (int ct = 0; ct < 4; ++ct) {
      int c0 = cbase0 + ct * 32;
      bool full = (c0 >= s) && (c0 + 32 <= e);
      float v0, v1;
      if (full) {
        v0 = max16(acc[0][ct]);
        v1 = max16(acc[1][ct]);
      } else {
        v0 = -INFINITY; v1 = -INFINITY;
#pragma unroll
        for (int r = 0; r < 16; ++r) {
          int code = c0 + (r & 3) + 8 * (r >> 2) + 4 * half;
          if (code >= s && code < e) {
            v0 = fmaxf(v0, acc[0][ct][r]);
            v1 = fmaxf(v1, acc[1][ct][r]);
          }
        }
      }
      v0 = fmaxf(v0, __shfl_xor(v0, 32, 64));    // chunk max in f32 acc space
      v1 = fmaxf(v1, __shfl_xor(v1, 32, 64));
      float t0 = v0 - WINDOW * 0.5f;             // acc>=t  <=>  g_bf<=chunkmin+W
      float t1 = v1 - WINDOW * 0.5f;
      unsigned b0 = 0, b1 = 0;
#pragma unroll
      for (int r = 0; r < 16; ++r) {
        int pos = (r & 3) + 8 * (r >> 2) + 4 * half;
        if (acc[0][ct][r] >= t0) b0 |= (1u << pos);
        if (acc[1][ct][r] >= t1) b1 |= (1u << pos);
      }
      b0 |= __shfl_xor(b0, 32, 64);              // merge row-half groups (uniform)
      b1 |= __shfl_xor(b1, 32, 64);
      float vs = half ? v1 : v0;                 // this thread's own token
      unsigned bs = half ? b1 : b0;
      unsigned short hh = f2h(-2.0f * vs);       // f16 chunk minimum (record value)
      float mvf = h2f(hh);
      lminf = fminf(lminf, mvf);
      if (mvf <= lminf + WINDOW) {               // running-window accept (reg-only)
        bmap |= 1ull << (nb * 4 + ct);
        unsigned mono = (unsigned)hh ^ ((hh & 0x8000u) ? 0xFFFFu : 0x8000u);
        unsigned p = (mono << 16) | (unsigned)(nb * 4 + ct);
        unsigned pm = bs;
        if (p < s8) {                            // static bubble insert of the PAIR
#define INS2_(SK, SM) { bool lt_ = p < (SK); unsigned tk_ = (SK), tm_ = (SM); \
          if (lt_) { (SK) = p; (SM) = pm; p = tk_; pm = tm_; } }
          INS2_(s0,m0) INS2_(s1,m1) INS2_(s2,m2) INS2_(s3,m3) INS2_(s4,m4)
          INS2_(s5,m5) INS2_(s6,m6) INS2_(s7,m7) INS2_(s8,m8)
#undef INS2_
        }
      }
    }
    __syncthreads();                             // Cs writes visible before next MFMA
  }

  // ---- emit record (ALL 64 lanes; token = tb*TTOK + wv*64 + lane; coalesced) ----
  {
    float thr = lminf + WINDOW;
    unsigned rec[8], msk[8];
#define EMIT_(J, S, M) { unsigned mono_ = (S) >> 16; \
    unsigned hh_ = (mono_ & 0x8000u) ? (mono_ ^ 0x8000u) : (mono_ ^ 0xFFFFu); \
    float v_ = h2f((unsigned short)hh_); \
    rec[J] = (v_ <= thr) ? ((hh_ << 16) | ((S) & 0xFFFFu)) : 0xFFFFFFFFu; \
    msk[J] = (M); }
    EMIT_(0, s0, m0) EMIT_(1, s1, m1) EMIT_(2, s2, m2) EMIT_(3, s3, m3)
    EMIT_(4, s4, m4) EMIT_(5, s5, m5) EMIT_(6, s6, m6) EMIT_(7, s7, m7)
#undef EMIT_
    {
      unsigned mono_ = s8 >> 16;
      unsigned hh_ = (mono_ & 0x8000u) ? (mono_ ^ 0x8000u) : (mono_ ^ 0xFFFFu);
      float v8 = h2f((unsigned short)hh_);       // NaN when <9 accepts -> false
      if (v8 <= thr) rec[7] = 0x0000FFFEu;       // EXACT overflow marker
    }
    int token = tb * TTOK + tokbase + lane;
#pragma unroll
    for (int j = 0; j < 8; ++j) {
      cand[(size_t)(cbk * 8 + j) * NTOK + token] = rec[j];
      cand[(size_t)(32 + cbk * 8 + j) * NTOK + token] = msk[j];
    }
    cand[(size_t)(64 + cbk * 2) * NTOK + token] = (unsigned)(bmap & 0xFFFFFFFFull);
    cand[(size_t)(65 + cbk * 2) * NTOK + token] = (unsigned)(bmap >> 32);
  }
}

// ---------------- pass 2: code-list rescue + fused epilogue (no brute force) --------
__global__ __launch_bounds__(256) void vq_rescue(
    const float* __restrict__ x, const float* __restrict__ cb,
    const float* __restrict__ sc, const unsigned int* __restrict__ cand,
    float* __restrict__ out_xq, float* __restrict__ out_idx,
    float* __restrict__ partial,
    const int* __restrict__ p_start, const int* __restrict__ p_end) {
#pragma clang fp contract(off)
  __shared__ float xsh[TOKB][64];                 // 4 KB staged x rows
  __shared__ float sxs[TOKB];                     // exact sx per token
  __shared__ unsigned short lst[TOKB][CCAP];      // per-token candidate CODE list
  __shared__ unsigned short clst[TOKB][KCAP];     // per-token chunk jobs (9216 B)
  __shared__ int ccnt[TOKB], kcnt[TOKB];
  int tid  = threadIdx.x;
  int wv   = tid >> 6;
  int lane = tid & 63;
  int blk  = blockIdx.x;
  int s = *p_start, e = *p_end;

  if (tid < TOKB) { ccnt[tid] = 0; kcnt[tid] = 0; }
#pragma unroll
  for (int p = 0; p < (TOKB * CCAP) / 256; ++p)   // sentinel-fill code list
    ((unsigned short*)lst)[tid + p * 256] = 0xFFFFu;
  __syncthreads();

  // ---- phase A (split across waves; one barrier) --------------------------------
  if (tid < 64) {
    // wave 0: slots+masks -> gthr -> per-token code list / chunk jobs
    int tl = tid >> 2, q = tid & 3;
    int gtok = blk * TOKB + tl;
    unsigned rv[8], mk[8];
#pragma unroll
    for (int j = 0; j < 8; ++j) {
      rv[j] = cand[(size_t)(q * 8 + j) * NTOK + gtok];
      mk[j] = cand[(size_t)(32 + q * 8 + j) * NTOK + gtok];
    }
    float m = INFINITY;
#pragma unroll
    for (int j = 0; j < 8; ++j) {
      unsigned cid = rv[j] & 0xFFFFu;
      float v = (cid < 64u) ? h2f((unsigned short)(rv[j] >> 16)) : INFINITY;
      m = fminf(m, v);
    }
    m = fminf(m, __shfl_xor(m, 1, 64));          // combine the token's 4 quarters
    m = fminf(m, __shfl_xor(m, 2, 64));
    float thr = m + WINDOW;                      // global window threshold
    bool marker = ((rv[7] & 0xFFFFu) == 0xFFFEu);
    if (!marker) {
#pragma unroll
      for (int j = 0; j < 8; ++j) {
        unsigned cid = rv[j] & 0xFFFFu;
        if (cid < 64u && h2f((unsigned short)(rv[j] >> 16)) <= thr) {
          unsigned bits = mk[j];
          int n = __popc(bits);
          int base = atomicAdd(&ccnt[tl], n);
          if (base + n <= CCAP) {                // push individual codes
            int kb = (q * 64 + (int)cid) * CSZ;
            while (bits) {
              int bpos = __ffs(bits) - 1; bits &= bits - 1;
              lst[tl][base++] = (unsigned short)(kb + bpos);
            }
          } else {                               // overflow: push whole chunk (exact)
            int kb2 = atomicAdd(&kcnt[tl], 1);
            if (kb2 < KCAP) clst[tl][kb2] = (unsigned short)(q * 64 + (int)cid);
          }
        }
      }
    } else {
      unsigned cid0 = rv[0] & 0xFFFFu;           // slot0 = quarter-local min
      float v0 = (cid0 < 64u) ? h2f((unsigned short)(rv[0] >> 16)) : INFINITY;
      if (v0 <= thr) {                           // quarter can contain survivors
        unsigned b0 = cand[(size_t)(64 + q * 2) * NTOK + gtok];
        unsigned b1 = cand[(size_t)(65 + q * 2) * NTOK + gtok];
        int n = __popc(b0) + __popc(b1);
        int base = atomicAdd(&kcnt[tl], n);
        while (b0) { int j = __ffs(b0) - 1; b0 &= b0 - 1;
          if (base < KCAP) clst[tl][base] = (unsigned short)(q * 64 + j); ++base; }
        while (b1) { int j = __ffs(b1) - 1; b1 &= b1 - 1;
          if (base < KCAP) clst[tl][base] = (unsigned short)(q * 64 + 32 + j); ++base; }
      }
    }
  } else if (tid < 192) {
    // waves 1-2: stage x rows (coalesced: 8 threads x 32B per 256B row)
    int t = tid - 64;
    int tl = t >> 3, seg = t & 7;
    const float4* xg = (const float4*)(x + (size_t)(blk * TOKB + tl) * EDIM + seg * 8);
    float4 A = xg[0], B = xg[1];
    *(float4*)&xsh[tl][seg * 8]     = A;
    *(float4*)&xsh[tl][seg * 8 + 4] = B;
  } else if (tid < 192 + TOKB) {
    // wave 3: exact sx per token (serial pairwise-8 replica, from global/L2)
    int tl = tid - 192;
    sxs[tl] = sx_of((const float4*)(x + (size_t)(blk * TOKB + tl) * EDIM));
  }
  __syncthreads();

  // exact single-code eval, 2 lanes/code: lane h5 covers t[4*h5..4*h5+3];
  // tt = s03 + s47 via shfl_xor(.,1) -- IEEE add commutative -> both lanes equal.
#define EVAL_CODE_BODY(K_, XL4) do {                                           \
    const float4* c4_ = (const float4*)(cb + (size_t)(K_) * EDIM);             \
    float t0_=0.0f,t1_=0.0f,t2_=0.0f,t3_=0.0f;                                 \
    _Pragma("unroll")                                                          \
    for (int i_ = 0; i_ < 8; ++i_) {             /* elements ascending i */    \
      float4 v_ = c4_[2*i_ + h5_];                                             \
      float4 p_ = (XL4)[2*i_ + h5_];                                           \
      t0_ += v_.x * p_.x; t1_ += v_.y * p_.y;                                  \
      t2_ += v_.z * p_.z; t3_ += v_.w * p_.w;                                  \
    }                                                                          \
    s2_ = (t0_ + t1_) + (t2_ + t3_);             /* s03 (h5=0) / s47 (h5=1) */ \
  } while (0)

#define FINISH_CODE(K_, ACT, SX, BP) do {                                      \
    float tt_ = s2_ + __shfl_xor(s2_, 1, 64);                                  \
    if ((ACT) && (K_) >= s && (K_) < e) {                                      \
      float d_ = ((SX) + sc[K_]) - 2.0f * tt_;                                 \
      unsigned db_ = __float_as_uint(d_);                                      \
      unsigned en_ = db_ ^ ((unsigned)((int)db_ >> 31) | 0x80000000u);         \
      unsigned long long pk_ = ((unsigned long long)en_ << 32) | (unsigned)(K_);\
      if (pk_ < (BP)) (BP) = pk_;                                              \
    }                                                                          \
  } while (0)

  // ---- phase B: wave wv owns tokens 4wv..4wv+3 (= one legacy partial group) -----
  float sg[4];
#pragma unroll
  for (int ti = 0; ti < 4; ++ti) {
    int tl = wv * 4 + ti;
    int gtok = blk * TOKB + tl;
    const float4* xl4 = (const float4*)xsh[tl];
    float sx = sxs[tl];
    unsigned long long bp = ~0ull;
    int ci_ = lane >> 1, h5_ = lane & 1;
    int nc = ccnt[tl]; if (nc > CCAP) nc = CCAP;
    for (int b0 = 0; b0 < nc; b0 += 32) {        // usually exactly one batch
      int nb = nc - b0; if (nb > 32) nb = 32;
      int kraw = (ci_ < nb) ? (int)lst[tl][b0 + ci_] : 0xFFFF;
      bool act = (kraw != 0xFFFF);               // sentinel = unwritten slot
      int k_ = act ? kraw : 0;
      float s2_ = 0.0f;
      if (act) EVAL_CODE_BODY(k_, xl4);
      FINISH_CODE(k_, act, sx, bp);
    }
    int nk = kcnt[tl]; if (nk > KCAP) nk = KCAP;
    for (int i = 0; i < nk; ++i) {               // chunk jobs (bounded, no cliff)
      int k_ = (int)clst[tl][i] * CSZ + ci_;
      float s2_;
      EVAL_CODE_BODY(k_, xl4);
      FINISH_CODE(k_, true, sx, bp);
    }
#pragma unroll
    for (int off = 32; off >= 1; off >>= 1) {    // lex-min (d asc, k asc)
      unsigned long long o = __shfl_xor(bp, off, 64);
      if (o < bp) bp = o;
    }
    int bidx = (int)(unsigned)(bp & 0xFFFFFFFFull) & (N_E - 1);

    float xx = xsh[tl][lane];
    float qv = cb[(size_t)bidx * EDIM + lane];
    float diff = qv - xx;                              // fl(x_q - x)
    out_xq[(size_t)gtok * EDIM + lane] = xx + diff;    // fl(x + fl(x_q - x))
    if (lane == 0) out_idx[gtok] = (float)bidx;
    float l = diff * diff;
#pragma unroll
    for (int off = 32; off >= 1; off >>= 1) l += __shfl_down(l, off, 64);
    sg[ti] = l;                                  // legacy per-token tree
  }
#undef EVAL_CODE_BODY
#undef FINISH_CODE
  if (lane == 0)
    partial[blk * 4 + wv] = (sg[0] + sg[1]) + (sg[2] + sg[3]);
}

// ---------------- final loss reduction ----------------------------------------------
__global__ __launch_bounds__(256) void vq_loss(const float* __restrict__ partial,
                                               float* __restrict__ out_loss) {
  int tid = threadIdx.x;
  float s = 0.0f;
  for (int i = tid; i < NTOK / 4; i += 256) s += partial[i];
#pragma unroll
  for (int off = 32; off >= 1; off >>= 1) s += __shfl_down(s, off, 64);
  __shared__ float sdata[4];
  if ((tid & 63) == 0) sdata[tid >> 6] = s;
  __syncthreads();
  if (tid == 0) {
    float total = (sdata[0] + sdata[1]) + (sdata[2] + sdata[3]);
    float m = total * (1.0f / (float)NELEM);
    out_loss[0] = m + 0.25f * m;
  }
}

// ---------------- launch -------------------------------------------------------------
extern "C" void kernel_launch(void* const* d_in, const int* in_sizes, int n_in,
                              void* d_out, int out_size, void* d_ws, size_t ws_size,
                              hipStream_t stream) {
  const float* x  = (const float*)d_in[0];
  const float* cb = (const float*)d_in[1];
  const int* p_start = (const int*)d_in[2];
  const int* p_end   = (const int*)d_in[3];

  float* ws = (float*)d_ws;
  float* sc      = ws;                                            // 8192 f
  float* partial = ws + N_E;                                      // 8192 f
  unsigned short* cbf  = (unsigned short*)(ws + 2 * N_E);         // 8192*64 us (1MB)
  unsigned int*   cand = (unsigned int*)(cbf + (size_t)N_E * EDIM); // 72 planes x NTOK u32 (9.4MB)

  float* out      = (float*)d_out;
  float* out_xq   = out;                 // 2097152
  float* out_loss = out + NELEM;         // 1
  float* out_idx  = out + NELEM + 1;     // 32768

  vq_sc<<<N_E / 256, 256, 0, stream>>>(cb, sc, cbf);
  dim3 g1(NTOK / TTOK, N_E / TCODE);
  vq_pass1<<<g1, 256, 0, stream>>>(x, cbf, cand, p_start, p_end);
  vq_rescue<<<NTOK / TOKB, 256, 0, stream>>>(x, cb, sc, cand, out_xq, out_idx,
                                             partial, p_start, p_end);
  vq_loss<<<1, 256, 0, stream>>>(partial, out_loss);
}

// Round 9
// 178.994 us; speedup vs baseline: 1.7700x; 1.0228x over previous
//
#include <hip/hip_runtime.h>
#include <math.h>

// VectorQuantizer: x (32768,64) f32, codebook (8192,64) f32, start/end/use_sk ints.
// Outputs concat: x_q_st (2097152 f32) | loss (1 f32) | indices (32768 as f32 values).
//
// R18 == R17 resubmitted (R8 bench failure was infrastructural: container acquire
// failed twice, same signature as R5 which ran clean on resubmit; kernel re-audited:
// no hang paths, no OOB, KCAP structurally sufficient, shfl pairs uniform).
// R17: pass1 occupancy + epilogue-VALU attack (records per-EIGHTH).
//  - TCODE 2048->1024: grid (128,8)=1024 blocks -> up to 4 blocks/CU.
//  - acc[2][4](128 VGPR) -> acc[2][2]: each nb's 4 chunks as two {16-MFMA group ->
//    2-chunk epilogue} passes -> ~64 fewer live VGPRs -> __launch_bounds__(256,3).
//  - Dual-lminf (lm0,lm1 tracked by EVERY thread) makes the accept pair-uniform ->
//    the 64-op mask build + shfl_xor(32) merges run only under if(a0|a1)
//    (~20-25% of chunks). Mask VALUES unchanged -> exactness untouched.
//  vq_sc:    sc_k exact (pairwise-8 numpy replica, f32) + cb -> bf16 rows (K=64).
//  vq_pass1: 32x32x16 MFMA filter, block = 256 tokens x 1024 codes (eighth).
//            Per (token,eighth): running local min; REGISTER sorted slots s0..s8
//            (key = mono-f16<<16|cid5, mask32); 32-bit bitmap of running-window
//            accepts. Emit 8 slot + 8 mask + 1 bitmap planes (136 planes total).
//            Marker (rec[7].cid=0xFFFE) iff mv(s8) <= thr_final (EXACT >=9-in-
//            final-window); bitmap superset covers marker eighths.
//  vq_rescue: 2048 blocks x 16 tokens. Phase A: waves0-1 parse 128 (token,eighth)
//            units -> gthr = min+WINDOW -> per-token CODE list (~4 codes) + chunk
//            jobs (slot overflow -> chunk job; marker eighth -> bitmap chunk jobs;
//            KCAP=320 >= structural max 256 -> NO brute-force path). Waves 2-3:
//            stage x rows + exact sx. Phase B: wave owns tokens 4wv..4wv+3:
//            batched code eval at 2 lanes/code with the BIT-EXACT R1 numpy-replica
//            arithmetic (j0-3/j4-7 split, tt = s03+s47 via shfl_xor(.,1),
//            IEEE-commutative); lex-min (enc(d),k); fused epilogue with the EXACT
//            legacy loss tree (6x shfl_down, (s0+s1)+(s2+s3), partial[token>>2]).
// Exactness: ref argmin k*: g_bf(k*) <= chunkmin + 2*err_bf (1.6e-4) < chunkmin+W
// -> k* in its chunk's mask. Its chunk's mv <= gmin + budget < gthr -> chunk in
// slots (pushed as codes, or as a chunk job on list overflow) or marker fires and
// its bitmap chunk job covers it -> k* always evaluated exactly; range filtered by
// k in [s,e). Lex-min over a superset containing the reference argmin == reference.
// DO NOT change the exact-path arithmetic: inter-code d gaps are ~1 ulp of d.

#define N_E    8192
#define EDIM   64
#define NTOK   32768
#define NELEM  (NTOK * EDIM)
#define CSZ    32                  // chunk size
#define WINDOW 3e-4f
#define TTOK   256                 // pass-1 tokens per block
#define TCODE  1024                // pass-1 codes per block (eighth)
#define SROW   72                  // Cs stride (ushorts; 36 dwords == 4 mod 8)
#define TOKB   16                  // rescue tokens per block
#define CCAP   64                  // rescue per-token code-list capacity
#define KCAP   320                 // rescue per-token chunk-job capacity (>= 256)

typedef __attribute__((ext_vector_type(8)))  short          short8;
typedef __attribute__((ext_vector_type(8)))  unsigned short ushort8v;
typedef __attribute__((ext_vector_type(16))) float          f32x16;

__device__ __forceinline__ unsigned short f2bf(float f) {   // RTNE f32->bf16 bits
  unsigned int u = __float_as_uint(f);
  return (unsigned short)((u + 0x7FFFu + ((u >> 16) & 1u)) >> 16);
}
__device__ __forceinline__ unsigned short f2h(float f) {
  union { _Float16 h; unsigned short u; } cv; cv.h = (_Float16)f; return cv.u;
}
__device__ __forceinline__ float h2f(unsigned short b) {
  union { _Float16 h; unsigned short u; } cv; cv.u = b; return (float)cv.h;
}
__device__ __forceinline__ float max16(const f32x16 a) {   // v_max3-fusible chain
  float m = fmaxf(fmaxf(a[0], a[1]), a[2]);
  m = fmaxf(fmaxf(m, a[3]),  a[4]);
  m = fmaxf(fmaxf(m, a[5]),  a[6]);
  m = fmaxf(fmaxf(m, a[7]),  a[8]);
  m = fmaxf(fmaxf(m, a[9]),  a[10]);
  m = fmaxf(fmaxf(m, a[11]), a[12]);
  m = fmaxf(fmaxf(m, a[13]), a[14]);
  return fmaxf(m, a[15]);
}
// sx = np.sum(x*x) pairwise-8 replica (reads a 64-f32 row via float4*)
__device__ __forceinline__ float sx_of(const float4* xl4) {
#pragma clang fp contract(off)
  float a0=0,a1=0,a2=0,a3=0,a4=0,a5=0,a6=0,a7=0;
#pragma unroll
  for (int i = 0; i < 8; ++i) {
    float4 pA = xl4[2*i], pB = xl4[2*i+1];
    a0 += pA.x * pA.x; a1 += pA.y * pA.y; a2 += pA.z * pA.z; a3 += pA.w * pA.w;
    a4 += pB.x * pB.x; a5 += pB.y * pB.y; a6 += pB.z * pB.z; a7 += pB.w * pB.w;
  }
  return ((a0+a1) + (a2+a3)) + ((a4+a5) + (a6+a7));
}

// ---------------- sc (exact pairwise-8) + cb -> bf16 rows (K=64) --------------------
__global__ __launch_bounds__(256) void vq_sc(const float* __restrict__ cb,
                                             float* __restrict__ sc,
                                             unsigned short* __restrict__ cbf) {
#pragma clang fp contract(off)
  int r = blockIdx.x * 256 + threadIdx.x;
  const float4* c4 = (const float4*)(cb + (size_t)r * EDIM);
  float sval = sx_of(c4);
  sc[r] = sval;
  unsigned short* dst = cbf + (size_t)r * EDIM;
#pragma unroll
  for (int h = 0; h < 8; ++h) {
    float4 fA = c4[2*h], fB = c4[2*h+1];
    ushort8v o = {f2bf(fA.x), f2bf(fA.y), f2bf(fA.z), f2bf(fA.w),
                  f2bf(fB.x), f2bf(fB.y), f2bf(fB.z), f2bf(fB.w)};
    *(ushort8v*)&dst[h * 8] = o;
  }
}

// ---------------- pass 1: MFMA filter -> slot/mask/bitmap records (per eighth) ------
// Frags: A[m=lane&31][k=8*(lane>>5)+j] (codes), B same (tokens),
// D: col=lane&31 (token), row=(reg&3)+8*(reg>>2)+4*(lane>>5) (code).
// Plane layout (136 planes x NTOK u32): [0..63] slots (cbk*8+j), [64..127] masks
// (64+cbk*8+j), [128..135] bitmaps (128+cbk).
__global__ __launch_bounds__(256, 3) void vq_pass1(
    const float* __restrict__ x, const unsigned short* __restrict__ cbf,
    unsigned int* __restrict__ cand,
    const int* __restrict__ p_start, const int* __restrict__ p_end) {
  __shared__ unsigned short Cs[128 * SROW];     // 18432 B
  int tid = threadIdx.x;
  int tb = blockIdx.x;    // token split [0,128)
  int cbk = blockIdx.y;   // code split  [0,8)  (the "eighth")
  int s = *p_start, e = *p_end;

  int lane = tid & 63, wv = tid >> 6;
  int half = lane >> 5, ln = lane & 31;
  int tokbase = wv * 64;

  // ---- stage first code tile: 128 rows x 8 ushort8 (linear, coalesced) ----
  const ushort8v* cg0 = (const ushort8v*)(cbf + (size_t)cbk * TCODE * EDIM);
#pragma unroll
  for (int p = 0; p < 4; ++p) {
    int idx = tid + p * 256;
    int row = idx >> 3, h = idx & 7;
    *(ushort8v*)&Cs[row * SROW + h * 8] = cg0[idx];
  }

  // ---- B fragments straight from global (fused f32 -> bf16), both token groups ----
  short8 bfr[2][4];
#pragma unroll
  for (int tg = 0; tg < 2; ++tg) {
    const float* xrow =
        x + (size_t)(tb * TTOK + tokbase + tg * 32 + ln) * EDIM + half * 8;
#pragma unroll
    for (int ks = 0; ks < 4; ++ks) {
      float4 fA = *(const float4*)(xrow + ks * 16);
      float4 fB = *(const float4*)(xrow + ks * 16 + 4);
      short8 v = {(short)f2bf(fA.x), (short)f2bf(fA.y), (short)f2bf(fA.z),
                  (short)f2bf(fA.w), (short)f2bf(fB.x), (short)f2bf(fB.y),
                  (short)f2bf(fB.z), (short)f2bf(fB.w)};
      bfr[tg][ks] = v;
    }
  }
  __syncthreads();

  // slots for THIS thread's token (tg == half); dual running minima for BOTH tokens
  unsigned s0=~0u,s1=~0u,s2=~0u,s3=~0u,s4=~0u,s5=~0u,s6=~0u,s7=~0u,s8=~0u;
  unsigned m0=0,m1=0,m2=0,m3=0,m4=0,m5=0,m6=0,m7=0,m8=0;
  unsigned bmap = 0u;
  float lm0 = INFINITY, lm1 = INFINITY;         // pair-uniform running minima

  for (int nb = 0; nb < 8; ++nb) {
    ushort8v creg[4];
    if (nb < 7) {                                // prefetch next tile into registers
      const ushort8v* cg =
          (const ushort8v*)(cbf + ((size_t)cbk * TCODE + (nb + 1) * 128) * EDIM);
#pragma unroll
      for (int p = 0; p < 4; ++p) creg[p] = cg[tid + p * 256];
    }
    // two ct-pair passes: {16-MFMA group -> 2-chunk epilogue} (acc = 64 VGPRs)
#pragma unroll
    for (int cp = 0; cp < 2; ++cp) {
      f32x16 acc[2][2];
#pragma unroll
      for (int tg = 0; tg < 2; ++tg)
#pragma unroll
        for (int c2 = 0; c2 < 2; ++c2) acc[tg][c2] = (f32x16)0.0f;
#pragma unroll
      for (int ks = 0; ks < 4; ++ks)
#pragma unroll
        for (int c2 = 0; c2 < 2; ++c2) {
          int ct = cp * 2 + c2;
          short8 a = *(const short8*)&Cs[(ct*32 + ln) * SROW + ks*16 + half*8];
          acc[0][c2] = __builtin_amdgcn_mfma_f32_32x32x16_bf16(a, bfr[0][ks],
                                                               acc[0][c2], 0, 0, 0);
          acc[1][c2] = __builtin_amdgcn_mfma_f32_32x32x16_bf16(a, bfr[1][ks],
                                                               acc[1][c2], 0, 0, 0);
        }
      // epilogue for these 2 chunks (registers only)
#pragma unroll
      for (int c2 = 0; c2 < 2; ++c2) {
        int cidL = nb * 4 + cp * 2 + c2;         // local chunk id (0..31)
        int c0 = cbk * TCODE + cidL * 32;
        bool full = (c0 >= s) && (c0 + 32 <= e);
        float v0, v1;
        if (full) {
          v0 = max16(acc[0][c2]);
          v1 = max16(acc[1][c2]);
        } else {
          v0 = -INFINITY; v1 = -INFINITY;
#pragma unroll
          for (int r = 0; r < 16; ++r) {
            int code = c0 + (r & 3) + 8 * (r >> 2) + 4 * half;
            if (code >= s && code < e) {
              v0 = fmaxf(v0, acc[0][c2][r]);
              v1 = fmaxf(v1, acc[1][c2][r]);
            }
          }
        }
        v0 = fmaxf(v0, __shfl_xor(v0, 32, 64));  // chunk max in f32 acc space
        v1 = fmaxf(v1, __shfl_xor(v1, 32, 64));
        unsigned short hh0 = f2h(-2.0f * v0);    // f16 chunk minima (record values)
        unsigned short hh1 = f2h(-2.0f * v1);
        float mv0 = h2f(hh0), mv1 = h2f(hh1);
        lm0 = fminf(lm0, mv0);                   // pair-uniform updates
        lm1 = fminf(lm1, mv1);
        bool a0 = (mv0 <= lm0 + WINDOW);         // pair-uniform accepts
        bool a1 = (mv1 <= lm1 + WINDOW);
        unsigned b0 = 0, b1 = 0;
        if (a0 | a1) {                           // pair-uniform branch: shfl safe
          float t0 = v0 - WINDOW * 0.5f;         // acc>=t  <=>  g_bf<=chunkmin+W
          float t1 = v1 - WINDOW * 0.5f;
#pragma unroll
          for (int r = 0; r < 16; ++r) {
            int pos = (r & 3) + 8 * (r >> 2) + 4 * half;
            if (acc[0][c2][r] >= t0) b0 |= (1u << pos);
            if (acc[1][c2][r] >= t1) b1 |= (1u << pos);
          }
          b0 |= __shfl_xor(b0, 32, 64);          // merge row-half groups
          b1 |= __shfl_xor(b1, 32, 64);
        }
        bool aown = half ? a1 : a0;
        if (aown) {                              // own-token slot insert
          bmap |= 1u << cidL;
          unsigned short hh = half ? hh1 : hh0;
          unsigned bs = half ? b1 : b0;
          unsigned mono = (unsigned)hh ^ ((hh & 0x8000u) ? 0xFFFFu : 0x8000u);
          unsigned p = (mono << 16) | (unsigned)cidL;
          unsigned pm = bs;
          if (p < s8) {                          // static bubble insert of the PAIR
#define INS2_(SK, SM) { bool lt_ = p < (SK); unsigned tk_ = (SK), tm_ = (SM); \
            if (lt_) { (SK) = p; (SM) = pm; p = tk_; pm = tm_; } }
            INS2_(s0,m0) INS2_(s1,m1) INS2_(s2,m2) INS2_(s3,m3) INS2_(s4,m4)
            INS2_(s5,m5) INS2_(s6,m6) INS2_(s7,m7) INS2_(s8,m8)
#undef INS2_
          }
        }
      }
    }
    __syncthreads();                             // all Cs reads done
    if (nb < 7) {
#pragma unroll
      for (int p = 0; p < 4; ++p) {
        int idx = tid + p * 256;
        int row = idx >> 3, h = idx & 7;
        *(ushort8v*)&Cs[row * SROW + h * 8] = creg[p];
      }
    }
    __syncthreads();                             // Cs writes visible before next MFMA
  }

  // ---- emit record (ALL 64 lanes; token = tb*TTOK + wv*64 + lane; coalesced) ----
  {
    float lminf = half ? lm1 : lm0;
    float thr = lminf + WINDOW;
    unsigned rec[8], msk[8];
#define EMIT_(J, S, M) { unsigned mono_ = (S) >> 16; \
    unsigned hh_ = (mono_ & 0x8000u) ? (mono_ ^ 0x8000u) : (mono_ ^ 0xFFFFu); \
    float v_ = h2f((unsigned short)hh_); \
    rec[J] = (v_ <= thr) ? ((hh_ << 16) | ((S) & 0xFFFFu)) : 0xFFFFFFFFu; \
    msk[J] = (M); }
    EMIT_(0, s0, m0) EMIT_(1, s1, m1) EMIT_(2, s2, m2) EMIT_(3, s3, m3)
    EMIT_(4, s4, m4) EMIT_(5, s5, m5) EMIT_(6, s6, m6) EMIT_(7, s7, m7)
#undef EMIT_
    {
      unsigned mono_ = s8 >> 16;
      unsigned hh_ = (mono_ & 0x8000u) ? (mono_ ^ 0x8000u) : (mono_ ^ 0xFFFFu);
      float v8 = h2f((unsigned short)hh_);       // NaN when <9 accepts -> false
      if (v8 <= thr) rec[7] = 0x0000FFFEu;       // EXACT overflow marker
    }
    int token = tb * TTOK + tokbase + lane;
#pragma unroll
    for (int j = 0; j < 8; ++j) {
      cand[(size_t)(cbk * 8 + j) * NTOK + token] = rec[j];
      cand[(size_t)(64 + cbk * 8 + j) * NTOK + token] = msk[j];
    }
    cand[(size_t)(128 + cbk) * NTOK + token] = bmap;
  }
}

// ---------------- pass 2: code-list rescue + fused epilogue (no brute force) --------
__global__ __launch_bounds__(256) void vq_rescue(
    const float* __restrict__ x, const float* __restrict__ cb,
    const float* __restrict__ sc, const unsigned int* __restrict__ cand,
    float* __restrict__ out_xq, float* __restrict__ out_idx,
    float* __restrict__ partial,
    const int* __restrict__ p_start, const int* __restrict__ p_end) {
#pragma clang fp contract(off)
  __shared__ float xsh[TOKB][64];                 // 4 KB staged x rows
  __shared__ float sxs[TOKB];                     // exact sx per token
  __shared__ unsigned short lst[TOKB][CCAP];      // per-token candidate CODE list
  __shared__ unsigned short clst[TOKB][KCAP];     // per-token chunk jobs (10240 B)
  __shared__ int ccnt[TOKB], kcnt[TOKB];
  int tid  = threadIdx.x;
  int wv   = tid >> 6;
  int lane = tid & 63;
  int blk  = blockIdx.x;
  int s = *p_start, e = *p_end;

  if (tid < TOKB) { ccnt[tid] = 0; kcnt[tid] = 0; }
#pragma unroll
  for (int p = 0; p < (TOKB * CCAP) / 256; ++p)   // sentinel-fill code list
    ((unsigned short*)lst)[tid + p * 256] = 0xFFFFu;
  __syncthreads();

  // ---- phase A (split across waves; one barrier) --------------------------------
  if (tid < 128) {
    // waves 0-1: 128 (token, eighth) units -> gthr -> code list / chunk jobs
    int tl = tid >> 3, q = tid & 7;
    int gtok = blk * TOKB + tl;
    unsigned rv[8], mk[8];
#pragma unroll
    for (int j = 0; j < 8; ++j) {
      rv[j] = cand[(size_t)(q * 8 + j) * NTOK + gtok];
      mk[j] = cand[(size_t)(64 + q * 8 + j) * NTOK + gtok];
    }
    float m = INFINITY;
#pragma unroll
    for (int j = 0; j < 8; ++j) {
      unsigned cid = rv[j] & 0xFFFFu;
      float v = (cid < 32u) ? h2f((unsigned short)(rv[j] >> 16)) : INFINITY;
      m = fminf(m, v);
    }
    m = fminf(m, __shfl_xor(m, 1, 64));          // combine the token's 8 eighths
    m = fminf(m, __shfl_xor(m, 2, 64));
    m = fminf(m, __shfl_xor(m, 4, 64));
    float thr = m + WINDOW;                      // global window threshold
    bool marker = ((rv[7] & 0xFFFFu) == 0xFFFEu);
    if (!marker) {
#pragma unroll
      for (int j = 0; j < 8; ++j) {
        unsigned cid = rv[j] & 0xFFFFu;
        if (cid < 32u && h2f((unsigned short)(rv[j] >> 16)) <= thr) {
          unsigned bits = mk[j];
          int n = __popc(bits);
          int base = atomicAdd(&ccnt[tl], n);
          if (base + n <= CCAP) {                // push individual codes
            int kb = (q * 32 + (int)cid) * CSZ;
            while (bits) {
              int bpos = __ffs(bits) - 1; bits &= bits - 1;
              lst[tl][base++] = (unsigned short)(kb + bpos);
            }
          } else {                               // overflow: push whole chunk (exact)
            int kb2 = atomicAdd(&kcnt[tl], 1);
            if (kb2 < KCAP) clst[tl][kb2] = (unsigned short)(q * 32 + (int)cid);
          }
        }
      }
    } else {
      unsigned cid0 = rv[0] & 0xFFFFu;           // slot0 = eighth-local min
      float v0 = (cid0 < 32u) ? h2f((unsigned short)(rv[0] >> 16)) : INFINITY;
      if (v0 <= thr) {                           // eighth can contain survivors
        unsigned b0 = cand[(size_t)(128 + q) * NTOK + gtok];
        int n = __popc(b0);
        int base = atomicAdd(&kcnt[tl], n);
        while (b0) { int j = __ffs(b0) - 1; b0 &= b0 - 1;
          if (base < KCAP) clst[tl][base] = (unsigned short)(q * 32 + j); ++base; }
      }
    }
  } else if (tid < 192) {
    // wave 2: stage x rows (coalesced: 4 threads x 64B per 256B row)
    int t = tid - 128;                           // 0..63
#pragma unroll
    for (int p = 0; p < 4; ++p) {
      int idx = t + p * 64;                      // 0..255 float4 units
      int tl = idx >> 4, seg = idx & 15;
      *(float4*)&xsh[tl][seg * 4] =
          ((const float4*)(x + (size_t)(blk * TOKB + tl) * EDIM))[seg];
    }
  } else if (tid < 192 + TOKB) {
    // wave 3: exact sx per token (serial pairwise-8 replica, from global/L2)
    int tl = tid - 192;
    sxs[tl] = sx_of((const float4*)(x + (size_t)(blk * TOKB + tl) * EDIM));
  }
  __syncthreads();

  // exact single-code eval, 2 lanes/code: lane h5 covers t[4*h5..4*h5+3];
  // tt = s03 + s47 via shfl_xor(.,1) -- IEEE add commutative -> both lanes equal.
#define EVAL_CODE_BODY(K_, XL4) do {                                           \
    const float4* c4_ = (const float4*)(cb + (size_t)(K_) * EDIM);             \
    float t0_=0.0f,t1_=0.0f,t2_=0.0f,t3_=0.0f;                                 \
    _Pragma("unroll")                                                          \
    for (int i_ = 0; i_ < 8; ++i_) {             /* elements ascending i */    \
      float4 v_ = c4_[2*i_ + h5_];                                             \
      float4 p_ = (XL4)[2*i_ + h5_];                                           \
      t0_ += v_.x * p_.x; t1_ += v_.y * p_.y;                                  \
      t2_ += v_.z * p_.z; t3_ += v_.w * p_.w;                                  \
    }                                                                          \
    s2_ = (t0_ + t1_) + (t2_ + t3_);             /* s03 (h5=0) / s47 (h5=1) */ \
  } while (0)

#define FINISH_CODE(K_, ACT, SX, BP) do {                                      \
    float tt_ = s2_ + __shfl_xor(s2_, 1, 64);                                  \
    if ((ACT) && (K_) >= s && (K_) < e) {                                      \
      float d_ = ((SX) + sc[K_]) - 2.0f * tt_;                                 \
      unsigned db_ = __float_as_uint(d_);                                      \
      unsigned en_ = db_ ^ ((unsigned)((int)db_ >> 31) | 0x80000000u);         \
      unsigned long long pk_ = ((unsigned long long)en_ << 32) | (unsigned)(K_);\
      if (pk_ < (BP)) (BP) = pk_;                                              \
    }                                                                          \
  } while (0)

  // ---- phase B: wave wv owns tokens 4wv..4wv+3 (= one legacy partial group) -----
  float sg[4];
#pragma unroll
  for (int ti = 0; ti < 4; ++ti) {
    int tl = wv * 4 + ti;
    int gtok = blk * TOKB + tl;
    const float4* xl4 = (const float4*)xsh[tl];
    float sx = sxs[tl];
    unsigned long long bp = ~0ull;
    int ci_ = lane >> 1, h5_ = lane & 1;
    int nc = ccnt[tl]; if (nc > CCAP) nc = CCAP;
    for (int b0 = 0; b0 < nc; b0 += 32) {        // usually exactly one batch
      int nb = nc - b0; if (nb > 32) nb = 32;
      int kraw = (ci_ < nb) ? (int)lst[tl][b0 + ci_] : 0xFFFF;
      bool act = (kraw != 0xFFFF);               // sentinel = unwritten slot
      int k_ = act ? kraw : 0;
      float s2_ = 0.0f;
      if (act) EVAL_CODE_BODY(k_, xl4);
      FINISH_CODE(k_, act, sx, bp);
    }
    int nk = kcnt[tl]; if (nk > KCAP) nk = KCAP;
    for (int i = 0; i < nk; ++i) {               // chunk jobs (bounded, no cliff)
      int k_ = (int)clst[tl][i] * CSZ + ci_;
      float s2_;
      EVAL_CODE_BODY(k_, xl4);
      FINISH_CODE(k_, true, sx, bp);
    }
#pragma unroll
    for (int off = 32; off >= 1; off >>= 1) {    // lex-min (d asc, k asc)
      unsigned long long o = __shfl_xor(bp, off, 64);
      if (o < bp) bp = o;
    }
    int bidx = (int)(unsigned)(bp & 0xFFFFFFFFull) & (N_E - 1);

    float xx = xsh[tl][lane];
    float qv = cb[(size_t)bidx * EDIM + lane];
    float diff = qv - xx;                              // fl(x_q - x)
    out_xq[(size_t)gtok * EDIM + lane] = xx + diff;    // fl(x + fl(x_q - x))
    if (lane == 0) out_idx[gtok] = (float)bidx;
    float l = diff * diff;
#pragma unroll
    for (int off = 32; off >= 1; off >>= 1) l += __shfl_down(l, off, 64);
    sg[ti] = l;                                  // legacy per-token tree
  }
#undef EVAL_CODE_BODY
#undef FINISH_CODE
  if (lane == 0)
    partial[blk * 4 + wv] = (sg[0] + sg[1]) + (sg[2] + sg[3]);
}

// ---------------- final loss reduction ----------------------------------------------
__global__ __launch_bounds__(256) void vq_loss(const float* __restrict__ partial,
                                               float* __restrict__ out_loss) {
  int tid = threadIdx.x;
  float s = 0.0f;
  for (int i = tid; i < NTOK / 4; i += 256) s += partial[i];
#pragma unroll
  for (int off = 32; off >= 1; off >>= 1) s += __shfl_down(s, off, 64);
  __shared__ float sdata[4];
  if ((tid & 63) == 0) sdata[tid >> 6] = s;
  __syncthreads();
  if (tid == 0) {
    float total = (sdata[0] + sdata[1]) + (sdata[2] + sdata[3]);
    float m = total * (1.0f / (float)NELEM);
    out_loss[0] = m + 0.25f * m;
  }
}

// ---------------- launch -------------------------------------------------------------
extern "C" void kernel_launch(void* const* d_in, const int* in_sizes, int n_in,
                              void* d_out, int out_size, void* d_ws, size_t ws_size,
                              hipStream_t stream) {
  const float* x  = (const float*)d_in[0];
  const float* cb = (const float*)d_in[1];
  const int* p_start = (const int*)d_in[2];
  const int* p_end   = (const int*)d_in[3];

  float* ws = (float*)d_ws;
  float* sc      = ws;                                            // 8192 f
  float* partial = ws + N_E;                                      // 8192 f
  unsigned short* cbf  = (unsigned short*)(ws + 2 * N_E);         // 8192*64 us (1MB)
  unsigned int*   cand = (unsigned int*)(cbf + (size_t)N_E * EDIM); // 136 planes x NTOK u32 (17.8MB)

  float* out      = (float*)d_out;
  float* out_xq   = out;                 // 2097152
  float* out_loss = out + NELEM;         // 1
  float* out_idx  = out + NELEM + 1;     // 32768

  vq_sc<<<N_E / 256, 256, 0, stream>>>(cb, sc, cbf);
  dim3 g1(NTOK / TTOK, N_E / TCODE);
  vq_pass1<<<g1, 256, 0, stream>>>(x, cbf, cand, p_start, p_end);
  vq_rescue<<<NTOK / TOKB, 256, 0, stream>>>(x, cb, sc, cand, out_xq, out_idx,
                                             partial, p_start, p_end);
  vq_loss<<<1, 256, 0, stream>>>(partial, out_loss);
}